// Round 1
// 283.607 us; speedup vs baseline: 1.1669x; 1.1669x over previous
//
#include <hip/hip_runtime.h>

#define HID 50
#define NMID 7
#define NT 4        // feature tiles (M dimension, 4*16 = 64 padded features)
#define NS 2        // K chunks of 32 (K = 64 slots: 50 features + 2 bias + 12 dead)
#define PT 4        // point tiles per wave (16 points each -> 64 points/wave)

// packed f16 params: Mid [L][t][s][64 lanes][8]; In [t][64][8]; Out [s][64][8]
#define MID_ELEMS (NMID * NT * NS * 64 * 8)   // 28672
#define IN_ELEMS  (NT * 64 * 8)               // 2048
#define OUT_ELEMS (NS * 64 * 8)               // 1024
#define W_HALFS   (MID_ELEMS + IN_ELEMS + OUT_ELEMS)

// 2*log2(e): folded into all tanh-layer weights so the epilogue is
// h = 1 - 2/(exp2(acc)+1) with no per-value multiply.
#define SCALE 2.8853900817779268f

typedef _Float16 half8  __attribute__((ext_vector_type(8)));
typedef float    f32x4  __attribute__((ext_vector_type(4)));

__device__ __forceinline__ unsigned short f16hi(float w) {
    _Float16 h = (_Float16)w;                    // RNE
    return __builtin_bit_cast(unsigned short, h);
}
__device__ __forceinline__ unsigned short f16lo(float w) {
    _Float16 h = (_Float16)w;
    _Float16 l = (_Float16)(w - (float)h);
    return __builtin_bit_cast(unsigned short, l);
}

// storage slot k (0..63) -> logical in-feature. k = 32s + 8q + j maps to
// fi = 16*(2s + (j>>2)) + 4q + (j&3). This is exactly the per-lane layout the
// producing layer's D fragment has (lane quad q holds rows 4q+r of tile t),
// so D feeds the next layer's B operand with zero cross-lane movement.
__device__ __forceinline__ int kperm(int k) {
    int s = k >> 5, q = (k >> 3) & 3, j = k & 7;
    return 16 * (2 * s + (j >> 2)) + 4 * q + (j & 3);
}

__global__ void pack_params(const float* __restrict__ W_in, const float* __restrict__ b_in,
                            const float* __restrict__ W_mid, const float* __restrict__ b_mid,
                            const float* __restrict__ W_out, const float* __restrict__ b_out,
                            unsigned short* __restrict__ wp) {
    int e = blockIdx.x * 256 + threadIdx.x;
    if (e < MID_ELEMS) {
        // A = (SCALE * W_mid[L])^T fragments: lane l -> out-feature row 16t+(l&15),
        // component j -> slot k = 32s + 8*(l>>4) + j. Slots 62/63 carry bias hi/lo
        // (their B values are the constant 1.0 injected by quad-3 lanes).
        int L = e / (NT * NS * 512), r1 = e % (NT * NS * 512);
        int t = r1 / (NS * 512),     r2 = r1 % (NS * 512);
        int s = r2 / 512,            r3 = r2 % 512;
        int l = r3 / 8,              j  = r3 % 8;
        int fo = t * 16 + (l & 15);
        int k  = s * 32 + ((l >> 4) << 3) + j;
        unsigned short bits = 0;
        if (fo < HID) {
            if (k == 62)      bits = f16hi(SCALE * b_mid[L * HID + fo]);
            else if (k == 63) bits = f16lo(SCALE * b_mid[L * HID + fo]);
            else {
                int fi = kperm(k);
                if (fi < HID) bits = f16hi(SCALE * W_mid[(L * HID + fi) * HID + fo]);
            }
        }
        wp[e] = bits;
    } else if (e < MID_ELEMS + IN_ELEMS) {
        // input layer: K=32, data only in k-octet 0 (quad 0 of B):
        // k 0..2 = W_in rows (hi act), 3..5 = W_in rows (lo act), 6/7 = bias hi/lo.
        int e2 = e - MID_ELEMS;
        int t = e2 / 512, r = e2 % 512, l = r / 8, j = r % 8;
        int fo = t * 16 + (l & 15);
        int q  = l >> 4;
        unsigned short bits = 0;
        if (fo < HID && q == 0) {
            if (j < 3)       bits = f16hi(SCALE * W_in[j * HID + fo]);
            else if (j < 6)  bits = f16hi(SCALE * W_in[(j - 3) * HID + fo]);
            else if (j == 6) bits = f16hi(SCALE * b_in[fo]);
            else             bits = f16lo(SCALE * b_in[fo]);
        }
        wp[e] = bits;
    } else if (e < W_HALFS) {
        // output layer: unscaled (no tanh after), rows 0..2 = out dims.
        int e3 = e - MID_ELEMS - IN_ELEMS;
        int s = e3 / 512, r = e3 % 512, l = r / 8, j = r % 8;
        int m = l & 15;
        int k = s * 32 + ((l >> 4) << 3) + j;
        unsigned short bits = 0;
        if (m < 3) {
            if (k == 62)      bits = f16hi(b_out[m]);
            else if (k == 63) bits = f16lo(b_out[m]);
            else {
                int fi = kperm(k);
                if (fi < HID) bits = f16hi(W_out[fi * 3 + m]);
            }
        }
        wp[e] = bits;
    }
}

__device__ __forceinline__ float tanh_e(float a) {
    // a is pre-scaled by 2*log2(e) via the packed weights.
    float e = __builtin_amdgcn_exp2f(a);
    float r = __builtin_amdgcn_rcpf(e + 1.0f);
    return __builtin_fmaf(r, -2.0f, 1.0f);       // tanh = 1 - 2/(e+1); tanh_e(0) == 0 exactly
}
__device__ __forceinline__ unsigned int pk2(float a, float b) {
    auto p = __builtin_amdgcn_cvt_pkrtz(a, b);
    return __builtin_bit_cast(unsigned int, p);
}
// chunk s=0: components j0..3 = tile0 rows 0..3, j4..7 = tile1 rows 0..3
__device__ __forceinline__ half8 epi_full(const f32x4& c0, const f32x4& c1) {
    uint4 u;
    u.x = pk2(tanh_e(c0[0]), tanh_e(c0[1]));
    u.y = pk2(tanh_e(c0[2]), tanh_e(c0[3]));
    u.z = pk2(tanh_e(c1[0]), tanh_e(c1[1]));
    u.w = pk2(tanh_e(c1[2]), tanh_e(c1[3]));
    return __builtin_bit_cast(half8, u);
}
// chunk s=1: tile2 rows 0..3, tile3 rows 0..1 (features 48/49 on quad 0);
// last word = constant (1.0,1.0): bias B-slots k=62/63 for quad 3, don't-care
// (zero A columns) for quads 0..2 -> 8 tanh and 1 cndmask saved per chunk pair.
__device__ __forceinline__ half8 epi_tail(const f32x4& c2, const f32x4& c3) {
    uint4 u;
    u.x = pk2(tanh_e(c2[0]), tanh_e(c2[1]));
    u.y = pk2(tanh_e(c2[2]), tanh_e(c2[3]));
    u.z = pk2(tanh_e(c3[0]), tanh_e(c3[1]));
    u.w = 0x3C003C00u;
    return __builtin_bit_cast(half8, u);
}

// Flipped-GEMM, fully register-resident MLP: A = W^T fragments (M = out-features),
// B = activations (N = points). D(col=point, row=4*quad+r of tile t) is per-lane
// exactly the next layer's B fragment under kperm(), so no LDS transpose exists.
__global__ __launch_bounds__(256, 4) void softmesh_mfma(
    const float* __restrict__ x, const float* __restrict__ y,
    const float* __restrict__ z,
    const unsigned short* __restrict__ wp,
    float* __restrict__ out, int n)
{
    const int tid  = threadIdx.x;
    const int wave = tid >> 6, lane = tid & 63;
    const int m = lane & 15, quad = lane >> 4;

    const int i0 = (blockIdx.x * 4 + wave) * 64;
    if (i0 >= n) return;

    const half8* __restrict__ Wm = (const half8*)wp;
    const half8* __restrict__ Wi = Wm + MID_ELEMS / 8;
    const half8* __restrict__ Wo = Wi + IN_ELEMS / 8;

    // input-layer weights + first mid-layer weights
    half8 Ain[NT];
#pragma unroll
    for (int t = 0; t < NT; ++t) Ain[t] = Wi[t * 64 + lane];
    half8 A[NT * NS];
#pragma unroll
    for (int i = 0; i < NT * NS; ++i) A[i] = Wm[i * 64 + lane];

    half8 B[PT][NS];   // activations, register-resident across all layers

    // ---- input layer: K=32, data in octet 0 (quad-0 lanes) ----
#pragma unroll
    for (int pt = 0; pt < PT; ++pt) {
        int idx = i0 + pt * 16 + m; if (idx >= n) idx = n - 1;
        half8 bf = {0, 0, 0, 0, 0, 0, 0, 0};
        if (quad == 0) {
            float xv = x[idx], yv = y[idx], zv = z[idx];
            _Float16 xh = (_Float16)xv, yh = (_Float16)yv, zh = (_Float16)zv;
            bf[0] = xh; bf[1] = yh; bf[2] = zh;
            bf[3] = (_Float16)(xv - (float)xh);
            bf[4] = (_Float16)(yv - (float)yh);
            bf[5] = (_Float16)(zv - (float)zh);
            bf[6] = (_Float16)1.0f; bf[7] = (_Float16)1.0f;   // bias hi/lo slots
        }
        f32x4 cc[NT];
#pragma unroll
        for (int t = 0; t < NT; ++t) {
            f32x4 z4 = (f32x4){0.f, 0.f, 0.f, 0.f};
            cc[t] = __builtin_amdgcn_mfma_f32_16x16x32_f16(Ain[t], bf, z4, 0, 0, 0);
        }
        B[pt][0] = epi_full(cc[0], cc[1]);
        B[pt][1] = epi_tail(cc[2], cc[3]);
    }

    // ---- 7 mid layers, fully unrolled; next-layer A prefetched ----
#pragma unroll
    for (int L = 0; L < NMID; ++L) {
        half8 An[NT * NS];
        if (L < NMID - 1) {
#pragma unroll
            for (int i = 0; i < NT * NS; ++i) An[i] = Wm[((L + 1) * NT * NS + i) * 64 + lane];
        } else {
            An[0] = Wo[lane]; An[1] = Wo[64 + lane];
#pragma unroll
            for (int i = 2; i < NT * NS; ++i) An[i] = A[i];   // dead
        }
#pragma unroll
        for (int pt = 0; pt < PT; ++pt) {
            f32x4 cc[NT];
#pragma unroll
            for (int t = 0; t < NT; ++t) {
                f32x4 z4 = (f32x4){0.f, 0.f, 0.f, 0.f};
                f32x4 c = __builtin_amdgcn_mfma_f32_16x16x32_f16(A[t * NS + 0], B[pt][0], z4, 0, 0, 0);
                cc[t]   = __builtin_amdgcn_mfma_f32_16x16x32_f16(A[t * NS + 1], B[pt][1], c,  0, 0, 0);
            }
            B[pt][0] = epi_full(cc[0], cc[1]);   // in-place: old B dead after MFMAs
            B[pt][1] = epi_tail(cc[2], cc[3]);
        }
#pragma unroll
        for (int i = 0; i < NT * NS; ++i) A[i] = An[i];
    }

    // ---- output layer: rows 0..2 of tile 0 = out dims, on quad-0 lanes ----
#pragma unroll
    for (int pt = 0; pt < PT; ++pt) {
        f32x4 z4 = (f32x4){0.f, 0.f, 0.f, 0.f};
        f32x4 c = __builtin_amdgcn_mfma_f32_16x16x32_f16(A[0], B[pt][0], z4, 0, 0, 0);
        c       = __builtin_amdgcn_mfma_f32_16x16x32_f16(A[1], B[pt][1], c,  0, 0, 0);
        if (quad == 0) {
            int idx = i0 + pt * 16 + m;
            if (idx < n) {
                out[idx] = c[0];
                out[(size_t)n + idx] = c[1];
                out[2 * (size_t)n + idx] = c[2];
            }
        }
    }
}

extern "C" void kernel_launch(void* const* d_in, const int* in_sizes, int n_in,
                              void* d_out, int out_size, void* d_ws, size_t ws_size,
                              hipStream_t stream) {
    const float* x     = (const float*)d_in[0];
    const float* y     = (const float*)d_in[1];
    const float* z     = (const float*)d_in[2];
    const float* W_in  = (const float*)d_in[3];
    const float* b_in  = (const float*)d_in[4];
    const float* W_mid = (const float*)d_in[5];
    const float* b_mid = (const float*)d_in[6];
    const float* W_out = (const float*)d_in[7];
    const float* b_out = (const float*)d_in[8];
    float* out = (float*)d_out;
    int n = in_sizes[0];

    unsigned short* wpp = (unsigned short*)d_ws;

    int pgrid = (W_HALFS + 255) / 256;
    pack_params<<<pgrid, 256, 0, stream>>>(W_in, b_in, W_mid, b_mid, W_out, b_out, wpp);

    int grid = (n + 255) / 256;   // 4 waves/block, 64 points/wave
    softmesh_mfma<<<grid, 256, 0, stream>>>(x, y, z, wpp, out, n);
}

// Round 2
// 264.613 us; speedup vs baseline: 1.2506x; 1.0718x over previous
//
#include <hip/hip_runtime.h>

#define HID 50
#define NMID 7
#define NT 4        // feature tiles (M dimension, 4*16 = 64 padded rows)
#define NS 2        // K chunks of 32 (K = 64 slots)
#define PT 4        // point tiles per wave (16 points each -> 64 points/wave)

// packed f16 params: Mid [L][t][s][64 lanes][8]; In [t][64][8]; Out [s][64][8]
#define MID_ELEMS (NMID * NT * NS * 64 * 8)   // 28672
#define IN_ELEMS  (NT * 64 * 8)               // 2048
#define OUT_ELEMS (NS * 64 * 8)               // 1024
#define W_HALFS   (MID_ELEMS + IN_ELEMS + OUT_ELEMS)

// 2*log2(e): folded into all tanh-layer weights. Additionally the producer
// bias carries a -1 so that exp2(a-1)+0.5 = (e^{2x}+1)/2, and the epilogue
// stores r' = rcp(exp2(a')+0.5) = 2/(e^{2x}+1) = 1 - tanh(x). Consumers use
// folded weights W' = -W, b' = b + sum_j W_j so the algebra is unchanged.
#define SCALE 2.8853900817779268f

typedef _Float16 half8  __attribute__((ext_vector_type(8)));
typedef float    f32x4  __attribute__((ext_vector_type(4)));
typedef float    f32x2  __attribute__((ext_vector_type(2)));

__device__ __forceinline__ unsigned short f16hi(float w) {
    _Float16 h = (_Float16)w;                    // RNE
    return __builtin_bit_cast(unsigned short, h);
}
__device__ __forceinline__ unsigned short f16lo(float w) {
    _Float16 h = (_Float16)w;
    _Float16 l = (_Float16)(w - (float)h);
    return __builtin_bit_cast(unsigned short, l);
}

// storage slot k (0..63) -> row index. k = 32s + 8q + j maps to
// row = 16*(2s + (j>>2)) + 4q + (j&3): exactly the producing D fragment's
// per-lane layout, so activations feed the next layer with no lane movement.
__device__ __forceinline__ int kperm(int k) {
    int s = k >> 5, q = (k >> 3) & 3, j = k & 7;
    return 16 * (2 * s + (j >> 2)) + 4 * q + (j & 3);
}

// 13-slice feature map: rows 0..47 = features 0..47 (tiles 0-2),
// row 48 (t3,q0,r0) = feature 48, row 52 (t3,q1,r0) = feature 49.
// Only slice (tile3, r=0) is live in the tail -> epilogue computes 13
// values per lane per point-tile instead of 14.
__device__ __forceinline__ int rowfeat(int rw) {
    if (rw < 48) return rw;
    if (rw == 48) return 48;
    if (rw == 52) return 49;
    return -1;
}

__global__ void pack_params(const float* __restrict__ W_in, const float* __restrict__ b_in,
                            const float* __restrict__ W_mid, const float* __restrict__ b_mid,
                            const float* __restrict__ W_out, const float* __restrict__ b_out,
                            unsigned short* __restrict__ wp) {
    int e = blockIdx.x * 256 + threadIdx.x;
    if (e < MID_ELEMS) {
        // A = -(SCALE * W_mid[L])^T; bias slot = SCALE*(b + sum_j W_j) - 1
        // (consumer-side 1-r' fold + producer-side exp2 halving fold).
        int L = e / (NT * NS * 512), r1 = e % (NT * NS * 512);
        int t = r1 / (NS * 512),     r2 = r1 % (NS * 512);
        int s = r2 / 512,            r3 = r2 % 512;
        int l = r3 / 8,              j  = r3 % 8;
        int fo = rowfeat(t * 16 + (l & 15));
        int k  = s * 32 + ((l >> 4) << 3) + j;
        unsigned short bits = 0;
        if (fo >= 0) {
            if (k >= 62) {
                float sum = b_mid[L * HID + fo];
                for (int jj = 0; jj < HID; ++jj) sum += W_mid[(L * HID + jj) * HID + fo];
                float v = SCALE * sum - 1.0f;
                bits = (k == 62) ? f16hi(v) : f16lo(v);
            } else {
                int fi = rowfeat(kperm(k));
                if (fi >= 0) bits = f16hi(-SCALE * W_mid[(L * HID + fi) * HID + fo]);
            }
        }
        wp[e] = bits;
    } else if (e < MID_ELEMS + IN_ELEMS) {
        // input layer consumes raw x,y,z: W keeps +SCALE; bias = SCALE*b - 1.
        // data only in k-octet 0 (quad 0 of B): k 0..2 = W rows (hi act),
        // 3..5 = W rows (lo act), 6/7 = bias hi/lo.
        int e2 = e - MID_ELEMS;
        int t = e2 / 512, r = e2 % 512, l = r / 8, j = r % 8;
        int fo = rowfeat(t * 16 + (l & 15));
        int q  = l >> 4;
        unsigned short bits = 0;
        if (fo >= 0 && q == 0) {
            if (j < 3)       bits = f16hi(SCALE * W_in[j * HID + fo]);
            else if (j < 6)  bits = f16hi(SCALE * W_in[(j - 3) * HID + fo]);
            else {
                float v = SCALE * b_in[fo] - 1.0f;
                bits = (j == 6) ? f16hi(v) : f16lo(v);
            }
        }
        wp[e] = bits;
    } else if (e < W_HALFS) {
        // output layer: no tanh after -> consumer fold only: W' = -W_out,
        // bias = b_out + sum_j W_out_j (hi/lo). Rows 0..2 = out dims.
        int e3 = e - MID_ELEMS - IN_ELEMS;
        int s = e3 / 512, r = e3 % 512, l = r / 8, j = r % 8;
        int m = l & 15;
        int k = s * 32 + ((l >> 4) << 3) + j;
        unsigned short bits = 0;
        if (m < 3) {
            if (k >= 62) {
                float sum = b_out[m];
                for (int jj = 0; jj < HID; ++jj) sum += W_out[jj * 3 + m];
                bits = (k == 62) ? f16hi(sum) : f16lo(sum);
            } else {
                int fi = rowfeat(kperm(k));
                if (fi >= 0) bits = f16hi(-W_out[fi * 3 + m]);
            }
        }
        wp[e] = bits;
    }
}

__device__ __forceinline__ unsigned int pk2(float a, float b) {
    auto p = __builtin_amdgcn_cvt_pkrtz(a, b);
    return __builtin_bit_cast(unsigned int, p);
}
// Pair epilogue with one shared rcp: r_i = d_other * rcp(d0*d1).
// f32x2 arithmetic invites v_pk_add_f32 / v_pk_mul_f32 (2 values per slot).
__device__ __forceinline__ unsigned int rr_pair(float a0, float a1) {
    f32x2 e;
    e[0] = __builtin_amdgcn_exp2f(a0);
    e[1] = __builtin_amdgcn_exp2f(a1);
    f32x2 d = e + 0.5f;
    float inv = __builtin_amdgcn_rcpf(d[0] * d[1]);
    f32x2 r = inv * __builtin_shufflevector(d, d, 1, 0);
    return pk2(r[0], r[1]);
}
// chunk s=0: j0..3 = tile0 rows 0..3, j4..7 = tile1 rows 0..3 (all live)
__device__ __forceinline__ half8 epi_full(const f32x4& c0, const f32x4& c1) {
    uint4 u;
    u.x = rr_pair(c0[0], c0[1]);
    u.y = rr_pair(c0[2], c0[3]);
    u.z = rr_pair(c1[0], c1[1]);
    u.w = rr_pair(c1[2], c1[3]);
    return __builtin_bit_cast(half8, u);
}
// chunk s=1: tile2 rows 0..3 live; tile3 only r=0 live (features 48/49 on
// quads 0/1). j5 is a dead slot (A column zero) and j6/j7 are the bias
// B-slots for quad 3 -> constants 1.0. 13 activations total per lane.
__device__ __forceinline__ half8 epi_tail(const f32x4& c2, const f32x4& c3) {
    uint4 u;
    u.x = rr_pair(c2[0], c2[1]);
    u.y = rr_pair(c2[2], c2[3]);
    float e = __builtin_amdgcn_exp2f(c3[0]);
    float r = __builtin_amdgcn_rcpf(e + 0.5f);
    u.z = pk2(r, 1.0f);
    u.w = 0x3C003C00u;
    return __builtin_bit_cast(half8, u);
}

// Flipped-GEMM, fully register-resident MLP: A = folded-W^T fragments
// (M = out-features), B = r'-activations (N = points). No LDS anywhere.
__global__ __launch_bounds__(256, 4) void softmesh_mfma(
    const float* __restrict__ x, const float* __restrict__ y,
    const float* __restrict__ z,
    const unsigned short* __restrict__ wp,
    float* __restrict__ out, int n)
{
    const int tid  = threadIdx.x;
    const int wave = tid >> 6, lane = tid & 63;
    const int m = lane & 15, quad = lane >> 4;

    const int i0 = (blockIdx.x * 4 + wave) * 64;
    if (i0 >= n) return;

    const half8* __restrict__ Wm = (const half8*)wp;
    const half8* __restrict__ Wi = Wm + MID_ELEMS / 8;
    const half8* __restrict__ Wo = Wi + IN_ELEMS / 8;

    half8 Ain[NT];
#pragma unroll
    for (int t = 0; t < NT; ++t) Ain[t] = Wi[t * 64 + lane];
    half8 A[NT * NS];
#pragma unroll
    for (int i = 0; i < NT * NS; ++i) A[i] = Wm[i * 64 + lane];

    half8 B[PT][NS];   // r'-activations, register-resident across all layers

    // ---- input layer: K=32, data in octet 0 (quad-0 lanes) ----
#pragma unroll
    for (int pt = 0; pt < PT; ++pt) {
        int idx = min(i0 + pt * 16 + m, n - 1);
        half8 bf = {0, 0, 0, 0, 0, 0, 0, 0};
        if (quad == 0) {
            float xv = x[idx], yv = y[idx], zv = z[idx];
            _Float16 xh = (_Float16)xv, yh = (_Float16)yv, zh = (_Float16)zv;
            bf[0] = xh; bf[1] = yh; bf[2] = zh;
            bf[3] = (_Float16)(xv - (float)xh);
            bf[4] = (_Float16)(yv - (float)yh);
            bf[5] = (_Float16)(zv - (float)zh);
            bf[6] = (_Float16)1.0f; bf[7] = (_Float16)1.0f;   // bias hi/lo slots
        }
        f32x4 cc[NT];
#pragma unroll
        for (int t = 0; t < NT; ++t) {
            f32x4 z4 = (f32x4){0.f, 0.f, 0.f, 0.f};
            cc[t] = __builtin_amdgcn_mfma_f32_16x16x32_f16(Ain[t], bf, z4, 0, 0, 0);
        }
        B[pt][0] = epi_full(cc[0], cc[1]);
        B[pt][1] = epi_tail(cc[2], cc[3]);
    }

    // ---- 7 mid layers, fully unrolled; next-layer A prefetched ----
#pragma unroll
    for (int L = 0; L < NMID; ++L) {
        half8 An[NT * NS];
        if (L < NMID - 1) {
#pragma unroll
            for (int i = 0; i < NT * NS; ++i) An[i] = Wm[((L + 1) * NT * NS + i) * 64 + lane];
        } else {
            An[0] = Wo[lane]; An[1] = Wo[64 + lane];
#pragma unroll
            for (int i = 2; i < NT * NS; ++i) An[i] = A[i];   // dead
        }
#pragma unroll
        for (int pt = 0; pt < PT; ++pt) {
            f32x4 cc[NT];
#pragma unroll
            for (int t = 0; t < NT; ++t) {
                f32x4 z4 = (f32x4){0.f, 0.f, 0.f, 0.f};
                f32x4 c = __builtin_amdgcn_mfma_f32_16x16x32_f16(A[t * NS + 0], B[pt][0], z4, 0, 0, 0);
                cc[t]   = __builtin_amdgcn_mfma_f32_16x16x32_f16(A[t * NS + 1], B[pt][1], c,  0, 0, 0);
            }
            B[pt][0] = epi_full(cc[0], cc[1]);   // in-place: old B dead after MFMAs
            B[pt][1] = epi_tail(cc[2], cc[3]);
        }
#pragma unroll
        for (int i = 0; i < NT * NS; ++i) A[i] = An[i];
    }

    // ---- output layer: rows 0..2 of tile 0 = out dims, on quad-0 lanes ----
#pragma unroll
    for (int pt = 0; pt < PT; ++pt) {
        f32x4 z4 = (f32x4){0.f, 0.f, 0.f, 0.f};
        f32x4 c = __builtin_amdgcn_mfma_f32_16x16x32_f16(A[0], B[pt][0], z4, 0, 0, 0);
        c       = __builtin_amdgcn_mfma_f32_16x16x32_f16(A[1], B[pt][1], c,  0, 0, 0);
        if (quad == 0) {
            int idx = i0 + pt * 16 + m;
            if (idx < n) {
                out[idx] = c[0];
                out[(size_t)n + idx] = c[1];
                out[2 * (size_t)n + idx] = c[2];
            }
        }
    }
}

extern "C" void kernel_launch(void* const* d_in, const int* in_sizes, int n_in,
                              void* d_out, int out_size, void* d_ws, size_t ws_size,
                              hipStream_t stream) {
    const float* x     = (const float*)d_in[0];
    const float* y     = (const float*)d_in[1];
    const float* z     = (const float*)d_in[2];
    const float* W_in  = (const float*)d_in[3];
    const float* b_in  = (const float*)d_in[4];
    const float* W_mid = (const float*)d_in[5];
    const float* b_mid = (const float*)d_in[6];
    const float* W_out = (const float*)d_in[7];
    const float* b_out = (const float*)d_in[8];
    float* out = (float*)d_out;
    int n = in_sizes[0];

    unsigned short* wpp = (unsigned short*)d_ws;

    int pgrid = (W_HALFS + 255) / 256;
    pack_params<<<pgrid, 256, 0, stream>>>(W_in, b_in, W_mid, b_mid, W_out, b_out, wpp);

    int grid = (n + 255) / 256;   // 4 waves/block, 64 points/wave
    softmesh_mfma<<<grid, 256, 0, stream>>>(x, y, z, wpp, out, n);
}